// Round 5
// baseline (604.594 us; speedup 1.0000x reference)
//
#include <hip/hip_runtime.h>

#define K_C    500
#define KPAD   512
#define DIM    768
#define NROWS  65536
#define BM     128
#define BK     32
#define NKT    (DIM / BK)      // 24 K-tiles
#define THREADS 512
#define TAU    0.75f

// Per-buffer LDS stride for B double-buffer: 4 chunks x 512 centers x 8 ushorts
#define BBUF_BYTES 32768

// ---- d_ws layout (bytes) ----
#define WS_CSQ  64
#define WS_LIST 4096
#define WS_CHI  270336
#define WS_CLO  (270336 + 786432)

typedef __attribute__((ext_vector_type(8)))  short bf16x8;
typedef __attribute__((ext_vector_type(16))) float f32x16;

__device__ __forceinline__ ushort f2bf(float f) {
    unsigned x = __float_as_uint(f);
    unsigned r = (x + 0x7fffu + ((x >> 16) & 1u)) >> 16;   // RNE
    return (ushort)r;
}
__device__ __forceinline__ float bf2f(ushort h) {
    return __uint_as_float(((unsigned)h) << 16);
}

#define GLOAD16(g, l)                                                        \
    __builtin_amdgcn_global_load_lds(                                        \
        (__attribute__((address_space(1))) void*)(g),                        \
        (__attribute__((address_space(3))) void*)(l), 16, 0, 0)

// ---------------------------------------------------------------------------
// Pre-kernel 1: centers fp32 -> (hi, lo) bf16, chunk-major tile layout
// unit u = kt*2048 + j*512 + r holds c[r][kt*32 + j*8 .. +7]. Zero-pads
// rows 500..511 and zeroes the rescue counter.
// ---------------------------------------------------------------------------
__global__ void convert_kernel(const float* __restrict__ c, ushort* __restrict__ chi,
                               ushort* __restrict__ clo, int* __restrict__ count) {
    int gid = blockIdx.x * 256 + threadIdx.x;
    if (gid == 0) *count = 0;
    int kt = gid >> 11;
    int u  = gid & 2047;
    int j  = u >> 9;
    int r  = u & 511;
    int kbase = kt * 32 + j * 8;

    ushort h[8], l[8];
    if (r < K_C) {
        #pragma unroll
        for (int e = 0; e < 8; ++e) {
            float v  = c[(size_t)r * DIM + kbase + e];
            ushort hb = f2bf(v);
            float  hv = bf2f(hb);
            ushort lb = f2bf(v - hv);
            h[e] = hb; l[e] = lb;
        }
    } else {
        #pragma unroll
        for (int e = 0; e < 8; ++e) { h[e] = 0; l[e] = 0; }
    }
    ushort* ph = chi + (size_t)gid * 8;
    ushort* pl = clo + (size_t)gid * 8;
    #pragma unroll
    for (int e = 0; e < 8; ++e) { ph[e] = h[e]; pl[e] = l[e]; }
}

// ---------------------------------------------------------------------------
// Pre-kernel 2: csq[k] = ||c_k||^2 fp32; pads 500..511 with +INF.
// ---------------------------------------------------------------------------
__global__ void csq_kernel(const float* __restrict__ c, float* __restrict__ csq) {
    int wid  = (blockIdx.x * blockDim.x + threadIdx.x) >> 6;
    int lane = threadIdx.x & 63;
    if (wid >= KPAD) return;
    if (wid >= K_C) { if (lane == 0) csq[wid] = INFINITY; return; }
    const float* row = c + (size_t)wid * DIM;
    float s = 0.f;
    #pragma unroll
    for (int j = 0; j < DIM / 64; ++j) {
        float v = row[lane + j * 64];
        s += v * v;
    }
    #pragma unroll
    for (int m = 32; m; m >>= 1) s += __shfl_xor(s, m, 64);
    if (lane == 0) csq[wid] = s;
}

// ---------------------------------------------------------------------------
// Main kernel: 128 rows x 512 centers per block. 8 waves = 2(m) x 4(n);
// per wave 2 Mfrags x 4 Nfrags of 32x32x16 MFMA.
// 2-TERM SPLIT (round 5): dots ~= xh*ch + xh*cl (dropped xl*ch term has
// dist-error sigma ~0.06, <=0.375 @6sigma; TAU=0.75 flags any row whose
// best/2nd margin could flip -> exact fp32 rescue).
// A: single bf16 (hi) staged via swizzled ds_write (slot = row ^ (chunk<<1),
// kills the 4-way write bank conflict). B: hi+lo double-buffered via
// global_load_lds prefetch issued at compute-phase start.
// ---------------------------------------------------------------------------
__global__ __launch_bounds__(THREADS, 2) void kmeans_mfma(
        const float* __restrict__ x, const char* __restrict__ ws,
        int* __restrict__ out) {
    __shared__ __align__(16) ushort Bh[2][4][KPAD][8];   // 64 KB
    __shared__ __align__(16) ushort Bl[2][4][KPAD][8];   // 64 KB
    __shared__ __align__(16) ushort Ah[4][BM][8];        // 8 KB
    __shared__ float rv1[4][BM];                         // 2 KB
    __shared__ float rv2[4][BM];                         // 2 KB
    __shared__ int   ridx[4][BM];                        // 2 KB

    const int tid  = threadIdx.x;
    const int w    = tid >> 6;          // wave 0..7
    const int lane = tid & 63;
    const int l31  = lane & 31;
    const int lh   = lane >> 5;
    const int wm   = w >> 2;            // 0..1 row half
    const int wn   = w & 3;             // 0..3 col quarter
    const int rowBase = blockIdx.x * BM;

    // A staging: thread t -> row t>>2 (0..127), k-chunk j = t&3
    const int srow = tid >> 2;
    const int sj   = tid & 3;
    const int sslot = srow ^ (sj << 1);   // bank-conflict-free write slot
    const float* xsrc = x + (size_t)(rowBase + srow) * DIM + sj * 8;

    const char* wsChi = ws + WS_CHI;
    const char* wsClo = ws + WS_CLO;
    const float* csq  = (const float*)(ws + WS_CSQ);
    int* count = (int*)ws;
    int* list  = (int*)(ws + WS_LIST);

    f32x16 acc[2][4] = {};

    // ---- prologue: stage B tile 0 into buf 0; load+convert A tile 0 ----
    {
        const char* sH = wsChi + w * 4096 + lane * 16;
        const char* sL = wsClo + w * 4096 + lane * 16;
        char* dH = ((char*)Bh) + w * 4096;
        char* dL = ((char*)Bl) + w * 4096;
        #pragma unroll
        for (int i = 0; i < 4; ++i) GLOAD16(sH + i * 1024, dH + i * 1024);
        #pragma unroll
        for (int i = 0; i < 4; ++i) GLOAD16(sL + i * 1024, dL + i * 1024);
    }
    uint4 hv;
    {
        float4 xa = *reinterpret_cast<const float4*>(xsrc);
        float4 xb = *reinterpret_cast<const float4*>(xsrc + 4);
        float v[8] = {xa.x, xa.y, xa.z, xa.w, xb.x, xb.y, xb.z, xb.w};
        uint h[8];
        #pragma unroll
        for (int e = 0; e < 8; ++e) h[e] = f2bf(v[e]);
        hv = make_uint4(h[0] | (h[1] << 16), h[2] | (h[3] << 16),
                        h[4] | (h[5] << 16), h[6] | (h[7] << 16));
    }

    for (int kt = 0; kt < NKT; ++kt) {
        const int cur = kt & 1;

        __syncthreads();   // (a) prev compute done; drains B[cur] stage + x loads

        // ---- A write phase (pre-converted regs -> LDS, swizzled slot) ----
        *reinterpret_cast<uint4*>(&Ah[sj][sslot][0]) = hv;

        __syncthreads();   // (b) A visible (lgkm drain only)

        // ---- prefetch next A floats FIRST (so end-of-loop convert waits
        //      vmcnt only down to these, leaving B stage in flight), then
        //      issue next B tile stage ----
        float4 xa, xb;
        if (kt + 1 < NKT) {
            xa = *reinterpret_cast<const float4*>(xsrc + (kt + 1) * BK);
            xb = *reinterpret_cast<const float4*>(xsrc + (kt + 1) * BK + 4);
            const int nxt = cur ^ 1;
            const char* sH = wsChi + (size_t)(kt + 1) * 32768 + w * 4096 + lane * 16;
            const char* sL = wsClo + (size_t)(kt + 1) * 32768 + w * 4096 + lane * 16;
            char* dH = ((char*)Bh) + nxt * BBUF_BYTES + w * 4096;
            char* dL = ((char*)Bl) + nxt * BBUF_BYTES + w * 4096;
            #pragma unroll
            for (int i = 0; i < 4; ++i) GLOAD16(sH + i * 1024, dH + i * 1024);
            #pragma unroll
            for (int i = 0; i < 4; ++i) GLOAD16(sL + i * 1024, dL + i * 1024);
        }

        // ---- compute: 2 k-steps of 16, 16 MFMAs each (2-term split) ----
        __builtin_amdgcn_s_setprio(1);
        #pragma unroll
        for (int ks = 0; ks < 2; ++ks) {
            const int j = ks * 2 + lh;
            const int rsl = l31 ^ (j << 1);          // read slot (swizzle inverse)
            const ushort* pAh = &Ah[j][wm * 64 + rsl][0];
            bf16x8 ah0 = *(const bf16x8*)pAh;
            bf16x8 ah1 = *(const bf16x8*)(pAh + 32 * 8);

            const ushort* pBh = &Bh[cur][j][wn * 128 + l31][0];
            const ushort* pBl = &Bl[cur][j][wn * 128 + l31][0];
            #pragma unroll
            for (int nf = 0; nf < 4; ++nf) {
                bf16x8 bh = *(const bf16x8*)(pBh + nf * 32 * 8);
                bf16x8 bl = *(const bf16x8*)(pBl + nf * 32 * 8);
                acc[0][nf] = __builtin_amdgcn_mfma_f32_32x32x16_bf16(ah0, bh, acc[0][nf], 0, 0, 0);
                acc[0][nf] = __builtin_amdgcn_mfma_f32_32x32x16_bf16(ah0, bl, acc[0][nf], 0, 0, 0);
                acc[1][nf] = __builtin_amdgcn_mfma_f32_32x32x16_bf16(ah1, bh, acc[1][nf], 0, 0, 0);
                acc[1][nf] = __builtin_amdgcn_mfma_f32_32x32x16_bf16(ah1, bl, acc[1][nf], 0, 0, 0);
            }
        }
        __builtin_amdgcn_s_setprio(0);

        // ---- convert next A tile (loads issued above; waits only x vmcnt) ----
        if (kt + 1 < NKT) {
            float v[8] = {xa.x, xa.y, xa.z, xa.w, xb.x, xb.y, xb.z, xb.w};
            uint h[8];
            #pragma unroll
            for (int e = 0; e < 8; ++e) h[e] = f2bf(v[e]);
            hv = make_uint4(h[0] | (h[1] << 16), h[2] | (h[3] << 16),
                            h[4] | (h[5] << 16), h[6] | (h[7] << 16));
        }
    }

    // ---- epilogue: per-row (best, second, idx) over this wave's 128 cols ----
    float cq[4];
    #pragma unroll
    for (int nf = 0; nf < 4; ++nf) cq[nf] = csq[wn * 128 + nf * 32 + l31];

    #pragma unroll
    for (int mf = 0; mf < 2; ++mf) {
        #pragma unroll
        for (int reg = 0; reg < 16; ++reg) {
            float v[4]; int col[4];
            #pragma unroll
            for (int nf = 0; nf < 4; ++nf) {
                v[nf]   = fmaf(-2.f, acc[mf][nf][reg], cq[nf]);
                col[nf] = wn * 128 + nf * 32 + l31;
            }
            // 4-way tournament for (best, idx, second); ties -> lower col
            float paL, paH; int paI;
            if (v[1] < v[0]) { paL = v[1]; paI = col[1]; paH = v[0]; }
            else             { paL = v[0]; paI = col[0]; paH = v[1]; }
            float pbL, pbH; int pbI;
            if (v[3] < v[2]) { pbL = v[3]; pbI = col[3]; pbH = v[2]; }
            else             { pbL = v[2]; pbI = col[2]; pbH = v[3]; }
            float b1, b2; int i1;
            if (pbL < paL) { b1 = pbL; i1 = pbI; b2 = fminf(paL, pbH); }
            else           { b1 = paL; i1 = paI; b2 = fminf(pbL, paH); }
            // reduce across the 32 l31 lanes (same lh half)
            #pragma unroll
            for (int m = 1; m < 32; m <<= 1) {
                float o1 = __shfl_xor(b1, m, 64);
                float o2 = __shfl_xor(b2, m, 64);
                int   oi = __shfl_xor(i1, m, 64);
                b2 = fminf(fminf(b2, o2), fmaxf(b1, o1));
                if (o1 < b1 || (o1 == b1 && oi < i1)) { b1 = o1; i1 = oi; }
            }
            int row = wm * 64 + mf * 32 + (reg & 3) + 8 * (reg >> 2) + 4 * lh;
            if (l31 == 0) { rv1[wn][row] = b1; rv2[wn][row] = b2; ridx[wn][row] = i1; }
        }
    }
    __syncthreads();

    // ---- merge 4 col-quarters per row, write out, flag tight margins ----
    if (tid < BM) {
        float b1 = INFINITY, b2 = INFINITY; int i1 = 0;
        #pragma unroll
        for (int ww = 0; ww < 4; ++ww) {
            float a1 = rv1[ww][tid], a2 = rv2[ww][tid];
            int   ai = ridx[ww][tid];
            b2 = fminf(fminf(b2, a2), fmaxf(b1, a1));
            if (a1 < b1 || (a1 == b1 && ai < i1)) { b1 = a1; i1 = ai; }
        }
        out[rowBase + tid] = i1;
        if (b2 - b1 < TAU) {
            int p = atomicAdd(count, 1);
            list[p] = rowBase + tid;
        }
    }
}

// ---------------------------------------------------------------------------
// Rescue: exact fp32 recompute for flagged rows (expected ~1-3% of rows).
// ---------------------------------------------------------------------------
__global__ void rescue_kernel(const float* __restrict__ x, const float* __restrict__ c,
                              const char* __restrict__ ws, int* __restrict__ out) {
    __shared__ float xrow[DIM];
    __shared__ float rv[256];
    __shared__ int   ri[256];
    const float* csq = (const float*)(ws + WS_CSQ);
    const int* list  = (const int*)(ws + WS_LIST);
    const int n = *(const int*)ws;
    const int tid = threadIdx.x;

    for (int it = blockIdx.x; it < n; it += gridDim.x) {
        int row = list[it];
        for (int d = tid; d < DIM; d += 256) xrow[d] = x[(size_t)row * DIM + d];
        __syncthreads();

        float bv = INFINITY; int bi = 0;
        for (int k = tid; k < K_C; k += 256) {
            const float* crow = c + (size_t)k * DIM;
            float dot = 0.f;
            #pragma unroll 4
            for (int d = 0; d < DIM; d += 4) {
                float4 cv = *reinterpret_cast<const float4*>(&crow[d]);
                dot = fmaf(xrow[d + 0], cv.x, dot);
                dot = fmaf(xrow[d + 1], cv.y, dot);
                dot = fmaf(xrow[d + 2], cv.z, dot);
                dot = fmaf(xrow[d + 3], cv.w, dot);
            }
            float dist = fmaf(-2.f, dot, csq[k]);
            if (dist < bv || (dist == bv && k < bi)) { bv = dist; bi = k; }
        }
        rv[tid] = bv; ri[tid] = bi;
        __syncthreads();
        for (int s = 128; s; s >>= 1) {
            if (tid < s) {
                if (rv[tid + s] < rv[tid] ||
                    (rv[tid + s] == rv[tid] && ri[tid + s] < ri[tid])) {
                    rv[tid] = rv[tid + s]; ri[tid] = ri[tid + s];
                }
            }
            __syncthreads();
        }
        if (tid == 0) out[row] = ri[0];
        __syncthreads();
    }
}

extern "C" void kernel_launch(void* const* d_in, const int* in_sizes, int n_in,
                              void* d_out, int out_size, void* d_ws, size_t ws_size,
                              hipStream_t stream) {
    const float* x = (const float*)d_in[0];
    const float* c = (const float*)d_in[1];
    char* ws = (char*)d_ws;
    int* out = (int*)d_out;

    convert_kernel<<<dim3(192), dim3(256), 0, stream>>>(
        c, (ushort*)(ws + WS_CHI), (ushort*)(ws + WS_CLO), (int*)ws);
    csq_kernel<<<dim3(128), dim3(256), 0, stream>>>(c, (float*)(ws + WS_CSQ));
    kmeans_mfma<<<dim3(NROWS / BM), dim3(THREADS), 0, stream>>>(x, ws, out);
    rescue_kernel<<<dim3(512), dim3(256), 0, stream>>>(x, c, ws, out);
}

// Round 6
// 289.525 us; speedup vs baseline: 2.0882x; 2.0882x over previous
//
#include <hip/hip_runtime.h>

#define K_C    500
#define KPAD   512
#define DIM    768
#define NROWS  65536
#define BM     128
#define BK     32
#define NKT    (DIM / BK)      // 24 K-tiles
#define THREADS 512
#define TAU    1.0f
#define RG     8               // rescue rows per group

// Per-buffer LDS stride for B double-buffer: 4 chunks x 512 centers x 8 ushorts
#define BBUF_BYTES 32768

// ---- d_ws layout (bytes) ----
#define WS_CSQ  64
#define WS_LIST 4096
#define WS_CHI  270336

typedef __attribute__((ext_vector_type(8)))  short bf16x8;
typedef __attribute__((ext_vector_type(16))) float f32x16;

__device__ __forceinline__ ushort f2bf(float f) {
    unsigned x = __float_as_uint(f);
    unsigned r = (x + 0x7fffu + ((x >> 16) & 1u)) >> 16;   // RNE
    return (ushort)r;
}

#define GLOAD16(g, l)                                                        \
    __builtin_amdgcn_global_load_lds(                                        \
        (__attribute__((address_space(1))) void*)(g),                        \
        (__attribute__((address_space(3))) void*)(l), 16, 0, 0)

// ---------------------------------------------------------------------------
// Pre-kernel 1: centers fp32 -> bf16 (RNE), chunk-major tile layout:
// unit u = kt*2048 + j*512 + r holds c[r][kt*32 + j*8 .. +7]. Zero-pads
// rows 500..511 and zeroes the rescue counter.
// ---------------------------------------------------------------------------
__global__ void convert_kernel(const float* __restrict__ c, ushort* __restrict__ chi,
                               int* __restrict__ count) {
    int gid = blockIdx.x * 256 + threadIdx.x;
    if (gid == 0) *count = 0;
    int kt = gid >> 11;
    int u  = gid & 2047;
    int j  = u >> 9;
    int r  = u & 511;
    int kbase = kt * 32 + j * 8;

    ushort h[8];
    if (r < K_C) {
        #pragma unroll
        for (int e = 0; e < 8; ++e) h[e] = f2bf(c[(size_t)r * DIM + kbase + e]);
    } else {
        #pragma unroll
        for (int e = 0; e < 8; ++e) h[e] = 0;
    }
    ushort* ph = chi + (size_t)gid * 8;
    #pragma unroll
    for (int e = 0; e < 8; ++e) ph[e] = h[e];
}

// ---------------------------------------------------------------------------
// Pre-kernel 2: csq[k] = ||c_k||^2 fp32; pads 500..511 with +INF.
// ---------------------------------------------------------------------------
__global__ void csq_kernel(const float* __restrict__ c, float* __restrict__ csq) {
    int wid  = (blockIdx.x * blockDim.x + threadIdx.x) >> 6;
    int lane = threadIdx.x & 63;
    if (wid >= KPAD) return;
    if (wid >= K_C) { if (lane == 0) csq[wid] = INFINITY; return; }
    const float* row = c + (size_t)wid * DIM;
    float s = 0.f;
    #pragma unroll
    for (int j = 0; j < DIM / 64; ++j) {
        float v = row[lane + j * 64];
        s += v * v;
    }
    #pragma unroll
    for (int m = 32; m; m >>= 1) s += __shfl_xor(s, m, 64);
    if (lane == 0) csq[wid] = s;
}

// ---------------------------------------------------------------------------
// Main kernel: 128 rows x 512 centers per block. 8 waves = 2(m) x 4(n);
// per wave 2 Mfrags x 4 Nfrags of 32x32x16 MFMA.
// 1-TERM (round 6): pure bf16 GEMM xh*ch. Margin-error sigma ~0.1; TAU=1.0
// (10 sigma) flags rows for exact fp32 rescue. Dropping Bl halves MFMA work
// and cuts LDS to 78 KB -> 2 blocks/CU -> cross-block phase overlap.
// A staged via swizzled ds_write (slot = row ^ (chunk<<1)); B double-buffered
// via global_load_lds prefetch issued at compute-phase start.
// ---------------------------------------------------------------------------
__global__ __launch_bounds__(THREADS, 2) void kmeans_mfma(
        const float* __restrict__ x, const char* __restrict__ ws,
        int* __restrict__ out) {
    __shared__ __align__(16) ushort Bh[2][4][KPAD][8];   // 64 KB
    __shared__ __align__(16) ushort Ah[4][BM][8];        // 8 KB
    __shared__ float rv1[4][BM];                         // 2 KB
    __shared__ float rv2[4][BM];                         // 2 KB
    __shared__ int   ridx[4][BM];                        // 2 KB

    const int tid  = threadIdx.x;
    const int w    = tid >> 6;          // wave 0..7
    const int lane = tid & 63;
    const int l31  = lane & 31;
    const int lh   = lane >> 5;
    const int wm   = w >> 2;            // 0..1 row half
    const int wn   = w & 3;             // 0..3 col quarter
    const int rowBase = blockIdx.x * BM;

    // A staging: thread t -> row t>>2 (0..127), k-chunk j = t&3
    const int srow = tid >> 2;
    const int sj   = tid & 3;
    const int sslot = srow ^ (sj << 1);   // bank-conflict-free write slot
    const float* xsrc = x + (size_t)(rowBase + srow) * DIM + sj * 8;

    const char* wsChi = ws + WS_CHI;
    const float* csq  = (const float*)(ws + WS_CSQ);
    int* count = (int*)ws;
    int* list  = (int*)(ws + WS_LIST);

    f32x16 acc[2][4] = {};

    // ---- prologue: stage B tile 0 into buf 0; load+convert A tile 0 ----
    {
        const char* sH = wsChi + w * 4096 + lane * 16;
        char* dH = ((char*)Bh) + w * 4096;
        #pragma unroll
        for (int i = 0; i < 4; ++i) GLOAD16(sH + i * 1024, dH + i * 1024);
    }
    uint4 hv;
    {
        float4 xa = *reinterpret_cast<const float4*>(xsrc);
        float4 xb = *reinterpret_cast<const float4*>(xsrc + 4);
        float v[8] = {xa.x, xa.y, xa.z, xa.w, xb.x, xb.y, xb.z, xb.w};
        uint h[8];
        #pragma unroll
        for (int e = 0; e < 8; ++e) h[e] = f2bf(v[e]);
        hv = make_uint4(h[0] | (h[1] << 16), h[2] | (h[3] << 16),
                        h[4] | (h[5] << 16), h[6] | (h[7] << 16));
    }

    for (int kt = 0; kt < NKT; ++kt) {
        const int cur = kt & 1;

        __syncthreads();   // (a) prev compute done; drains B[cur] stage + x loads

        // ---- A write phase (pre-converted regs -> LDS, swizzled slot) ----
        *reinterpret_cast<uint4*>(&Ah[sj][sslot][0]) = hv;

        __syncthreads();   // (b) A visible (lgkm drain only)

        // ---- prefetch next A floats first, then next B tile stage ----
        float4 xa, xb;
        if (kt + 1 < NKT) {
            xa = *reinterpret_cast<const float4*>(xsrc + (kt + 1) * BK);
            xb = *reinterpret_cast<const float4*>(xsrc + (kt + 1) * BK + 4);
            const int nxt = cur ^ 1;
            const char* sH = wsChi + (size_t)(kt + 1) * 32768 + w * 4096 + lane * 16;
            char* dH = ((char*)Bh) + nxt * BBUF_BYTES + w * 4096;
            #pragma unroll
            for (int i = 0; i < 4; ++i) GLOAD16(sH + i * 1024, dH + i * 1024);
        }

        // ---- compute: 2 k-steps of 16, 8 MFMAs each (1-term) ----
        __builtin_amdgcn_s_setprio(1);
        #pragma unroll
        for (int ks = 0; ks < 2; ++ks) {
            const int j = ks * 2 + lh;
            const int rsl = l31 ^ (j << 1);          // read slot (swizzle inverse)
            const ushort* pAh = &Ah[j][wm * 64 + rsl][0];
            bf16x8 ah0 = *(const bf16x8*)pAh;
            bf16x8 ah1 = *(const bf16x8*)(pAh + 32 * 8);

            const ushort* pBh = &Bh[cur][j][wn * 128 + l31][0];
            #pragma unroll
            for (int nf = 0; nf < 4; ++nf) {
                bf16x8 bh = *(const bf16x8*)(pBh + nf * 32 * 8);
                acc[0][nf] = __builtin_amdgcn_mfma_f32_32x32x16_bf16(ah0, bh, acc[0][nf], 0, 0, 0);
                acc[1][nf] = __builtin_amdgcn_mfma_f32_32x32x16_bf16(ah1, bh, acc[1][nf], 0, 0, 0);
            }
        }
        __builtin_amdgcn_s_setprio(0);

        // ---- convert next A tile (loads issued above) ----
        if (kt + 1 < NKT) {
            float v[8] = {xa.x, xa.y, xa.z, xa.w, xb.x, xb.y, xb.z, xb.w};
            uint h[8];
            #pragma unroll
            for (int e = 0; e < 8; ++e) h[e] = f2bf(v[e]);
            hv = make_uint4(h[0] | (h[1] << 16), h[2] | (h[3] << 16),
                            h[4] | (h[5] << 16), h[6] | (h[7] << 16));
        }
    }

    // ---- epilogue: per-row (best, second, idx) over this wave's 128 cols ----
    float cq[4];
    #pragma unroll
    for (int nf = 0; nf < 4; ++nf) cq[nf] = csq[wn * 128 + nf * 32 + l31];

    #pragma unroll
    for (int mf = 0; mf < 2; ++mf) {
        #pragma unroll
        for (int reg = 0; reg < 16; ++reg) {
            float v[4]; int col[4];
            #pragma unroll
            for (int nf = 0; nf < 4; ++nf) {
                v[nf]   = fmaf(-2.f, acc[mf][nf][reg], cq[nf]);
                col[nf] = wn * 128 + nf * 32 + l31;
            }
            float paL, paH; int paI;
            if (v[1] < v[0]) { paL = v[1]; paI = col[1]; paH = v[0]; }
            else             { paL = v[0]; paI = col[0]; paH = v[1]; }
            float pbL, pbH; int pbI;
            if (v[3] < v[2]) { pbL = v[3]; pbI = col[3]; pbH = v[2]; }
            else             { pbL = v[2]; pbI = col[2]; pbH = v[3]; }
            float b1, b2; int i1;
            if (pbL < paL) { b1 = pbL; i1 = pbI; b2 = fminf(paL, pbH); }
            else           { b1 = paL; i1 = paI; b2 = fminf(pbL, paH); }
            #pragma unroll
            for (int m = 1; m < 32; m <<= 1) {
                float o1 = __shfl_xor(b1, m, 64);
                float o2 = __shfl_xor(b2, m, 64);
                int   oi = __shfl_xor(i1, m, 64);
                b2 = fminf(fminf(b2, o2), fmaxf(b1, o1));
                if (o1 < b1 || (o1 == b1 && oi < i1)) { b1 = o1; i1 = oi; }
            }
            int row = wm * 64 + mf * 32 + (reg & 3) + 8 * (reg >> 2) + 4 * lh;
            if (l31 == 0) { rv1[wn][row] = b1; rv2[wn][row] = b2; ridx[wn][row] = i1; }
        }
    }
    __syncthreads();

    // ---- merge 4 col-quarters per row, write out, flag tight margins ----
    if (tid < BM) {
        float b1 = INFINITY, b2 = INFINITY; int i1 = 0;
        #pragma unroll
        for (int ww = 0; ww < 4; ++ww) {
            float a1 = rv1[ww][tid], a2 = rv2[ww][tid];
            int   ai = ridx[ww][tid];
            b2 = fminf(fminf(b2, a2), fmaxf(b1, a1));
            if (a1 < b1 || (a1 == b1 && ai < i1)) { b1 = a1; i1 = ai; }
        }
        out[rowBase + tid] = i1;
        if (b2 - b1 < TAU) {
            int p = atomicAdd(count, 1);
            list[p] = rowBase + tid;
        }
    }
}

// ---------------------------------------------------------------------------
// Rescue v2: exact fp32 recompute, 8 rows per block staged in LDS.
// Wave w owns centers [w*125, (w+1)*125); lane l covers dims l+64j (coalesced
// center reads, 2-way-free LDS x reads); butterfly reduce for the dot.
// Center traffic /8 vs v1 and fully coalesced.
// ---------------------------------------------------------------------------
__global__ __launch_bounds__(256) void rescue_kernel(
        const float* __restrict__ x, const float* __restrict__ c,
        const char* __restrict__ ws, int* __restrict__ out) {
    __shared__ float xs[RG][DIM];     // 24 KB
    __shared__ float wbv[4][RG];
    __shared__ int   wbi[4][RG];
    __shared__ int   rows_s[RG];
    const float* csq = (const float*)(ws + WS_CSQ);
    const int* list  = (const int*)(ws + WS_LIST);
    const int n = *(const int*)ws;
    const int tid  = threadIdx.x;
    const int w    = tid >> 6;
    const int lane = tid & 63;

    for (int g = blockIdx.x; g * RG < n; g += gridDim.x) {
        const int base = g * RG;
        const int cnt = min(RG, n - base);
        if (tid < cnt) rows_s[tid] = list[base + tid];
        __syncthreads();
        for (int idx = tid; idx < cnt * DIM; idx += 256) {
            int r = idx / DIM, d = idx - r * DIM;
            xs[r][d] = x[(size_t)rows_s[r] * DIM + d];
        }
        __syncthreads();

        float bv[RG]; int bi[RG];
        #pragma unroll
        for (int r = 0; r < RG; ++r) { bv[r] = INFINITY; bi[r] = 0; }

        const int k0 = w * 125, k1 = k0 + 125;
        for (int k = k0; k < k1; ++k) {
            const float* crow = c + (size_t)k * DIM;
            float cv[12];
            #pragma unroll
            for (int j = 0; j < 12; ++j) cv[j] = crow[lane + 64 * j];
            float p[RG];
            #pragma unroll
            for (int r = 0; r < RG; ++r) {
                float s = 0.f;
                #pragma unroll
                for (int j = 0; j < 12; ++j) s = fmaf(xs[r][lane + 64 * j], cv[j], s);
                p[r] = s;
            }
            #pragma unroll
            for (int m = 1; m < 64; m <<= 1) {
                #pragma unroll
                for (int r = 0; r < RG; ++r) p[r] += __shfl_xor(p[r], m, 64);
            }
            const float cq = csq[k];
            #pragma unroll
            for (int r = 0; r < RG; ++r) {
                float dist = fmaf(-2.f, p[r], cq);
                if (dist < bv[r]) { bv[r] = dist; bi[r] = k; }   // k ascending: ties keep lower
            }
        }
        if (lane == 0) {
            #pragma unroll
            for (int r = 0; r < RG; ++r) { wbv[w][r] = bv[r]; wbi[w][r] = bi[r]; }
        }
        __syncthreads();
        if (tid < cnt) {
            float b = wbv[0][tid]; int i = wbi[0][tid];
            #pragma unroll
            for (int ww = 1; ww < 4; ++ww) {    // ascending wave order: strict < keeps lower idx
                if (wbv[ww][tid] < b) { b = wbv[ww][tid]; i = wbi[ww][tid]; }
            }
            out[rows_s[tid]] = i;
        }
        __syncthreads();
    }
}

extern "C" void kernel_launch(void* const* d_in, const int* in_sizes, int n_in,
                              void* d_out, int out_size, void* d_ws, size_t ws_size,
                              hipStream_t stream) {
    const float* x = (const float*)d_in[0];
    const float* c = (const float*)d_in[1];
    char* ws = (char*)d_ws;
    int* out = (int*)d_out;

    convert_kernel<<<dim3(192), dim3(256), 0, stream>>>(
        c, (ushort*)(ws + WS_CHI), (int*)ws);
    csq_kernel<<<dim3(128), dim3(256), 0, stream>>>(c, (float*)(ws + WS_CSQ));
    kmeans_mfma<<<dim3(NROWS / BM), dim3(THREADS), 0, stream>>>(x, ws, out);
    rescue_kernel<<<dim3(512), dim3(256), 0, stream>>>(x, c, ws, out);
}

// Round 7
// 273.312 us; speedup vs baseline: 2.2121x; 1.0593x over previous
//
#include <hip/hip_runtime.h>

#define K_C    500
#define KPAD   512
#define DIM    768
#define NROWS  65536
#define BM     64
#define BK     32
#define NKT    (DIM / BK)      // 24 K-tiles
#define THREADS 512
#define TAU    1.0f
#define RG     8               // rescue rows per group

// Per-buffer LDS stride for B double-buffer: 4 chunks x 512 centers x 8 ushorts
#define BBUF_BYTES 32768

// ---- d_ws layout (bytes) ----
#define WS_CSQ  64
#define WS_LIST 4096
#define WS_CHI  270336

typedef __attribute__((ext_vector_type(8)))  short bf16x8;
typedef __attribute__((ext_vector_type(16))) float f32x16;

__device__ __forceinline__ ushort f2bf(float f) {
    unsigned x = __float_as_uint(f);
    unsigned r = (x + 0x7fffu + ((x >> 16) & 1u)) >> 16;   // RNE
    return (ushort)r;
}

#define GLOAD16(g, l)                                                        \
    __builtin_amdgcn_global_load_lds(                                        \
        (__attribute__((address_space(1))) void*)(g),                        \
        (__attribute__((address_space(3))) void*)(l), 16, 0, 0)

// ---------------------------------------------------------------------------
// Pre-kernel 1: centers fp32 -> bf16 (RNE), chunk-major tile layout:
// unit u = kt*2048 + j*512 + r holds c[r][kt*32 + j*8 .. +7]. Zero-pads
// rows 500..511 and zeroes the rescue counter.
// ---------------------------------------------------------------------------
__global__ void convert_kernel(const float* __restrict__ c, ushort* __restrict__ chi,
                               int* __restrict__ count) {
    int gid = blockIdx.x * 256 + threadIdx.x;
    if (gid == 0) *count = 0;
    int kt = gid >> 11;
    int u  = gid & 2047;
    int j  = u >> 9;
    int r  = u & 511;
    int kbase = kt * 32 + j * 8;

    ushort h[8];
    if (r < K_C) {
        #pragma unroll
        for (int e = 0; e < 8; ++e) h[e] = f2bf(c[(size_t)r * DIM + kbase + e]);
    } else {
        #pragma unroll
        for (int e = 0; e < 8; ++e) h[e] = 0;
    }
    ushort* ph = chi + (size_t)gid * 8;
    #pragma unroll
    for (int e = 0; e < 8; ++e) ph[e] = h[e];
}

// ---------------------------------------------------------------------------
// Pre-kernel 2: csq[k] = ||c_k||^2 fp32; pads 500..511 with +INF.
// ---------------------------------------------------------------------------
__global__ void csq_kernel(const float* __restrict__ c, float* __restrict__ csq) {
    int wid  = (blockIdx.x * blockDim.x + threadIdx.x) >> 6;
    int lane = threadIdx.x & 63;
    if (wid >= KPAD) return;
    if (wid >= K_C) { if (lane == 0) csq[wid] = INFINITY; return; }
    const float* row = c + (size_t)wid * DIM;
    float s = 0.f;
    #pragma unroll
    for (int j = 0; j < DIM / 64; ++j) {
        float v = row[lane + j * 64];
        s += v * v;
    }
    #pragma unroll
    for (int m = 32; m; m >>= 1) s += __shfl_xor(s, m, 64);
    if (lane == 0) csq[wid] = s;
}

// ---------------------------------------------------------------------------
// Main kernel (round 7): 64 rows x 512 centers per block, grid 1024.
// 8 waves = 2(m) x 4(n); per wave 1 Mfrag x 4 Nfrags -> acc only 64 regs.
// __launch_bounds__(512,4) caps regs at 128 -> 4 waves/SIMD -> 2 blocks/CU
// (LDS 71 KB). Cross-block overlap hides the stage/barrier/drain phases that
// dominated round 6 (MfmaUtil 11%, occupancy 22%).
// 1-term bf16 GEMM xh*ch; TAU=1.0 flags rows for exact fp32 rescue.
// ---------------------------------------------------------------------------
__global__ __launch_bounds__(THREADS, 4) void kmeans_mfma(
        const float* __restrict__ x, const char* __restrict__ ws,
        int* __restrict__ out) {
    __shared__ __align__(16) ushort Bh[2][4][KPAD][8];   // 64 KB
    __shared__ __align__(16) ushort Ah[4][BM][8];        // 4 KB
    __shared__ float rv1[4][BM];                         // 1 KB
    __shared__ float rv2[4][BM];                         // 1 KB
    __shared__ int   ridx[4][BM];                        // 1 KB

    const int tid  = threadIdx.x;
    const int w    = tid >> 6;          // wave 0..7
    const int lane = tid & 63;
    const int l31  = lane & 31;
    const int lh   = lane >> 5;
    const int wm   = w >> 2;            // 0..1 row half (32 rows each)
    const int wn   = w & 3;             // 0..3 col quarter (128 cols each)
    const int rowBase = blockIdx.x * BM;

    // A staging (threads 0..255): thread t -> row t>>2 (0..63), k-chunk j = t&3
    const int srow = tid >> 2;
    const int sj   = tid & 3;
    const int sslot = srow ^ (sj << 1);   // bank-conflict-free write slot
    const bool stager = (tid < 256);
    const float* xsrc = x + (size_t)(rowBase + srow) * DIM + sj * 8;

    const char* wsChi = ws + WS_CHI;
    const float* csq  = (const float*)(ws + WS_CSQ);
    int* count = (int*)ws;
    int* list  = (int*)(ws + WS_LIST);

    f32x16 acc[4] = {};

    // ---- prologue: stage B tile 0 into buf 0; load+convert A tile 0 ----
    {
        const char* sH = wsChi + w * 4096 + lane * 16;
        char* dH = ((char*)Bh) + w * 4096;
        #pragma unroll
        for (int i = 0; i < 4; ++i) GLOAD16(sH + i * 1024, dH + i * 1024);
    }
    uint4 hv;
    if (stager) {
        float4 xa = *reinterpret_cast<const float4*>(xsrc);
        float4 xb = *reinterpret_cast<const float4*>(xsrc + 4);
        float v[8] = {xa.x, xa.y, xa.z, xa.w, xb.x, xb.y, xb.z, xb.w};
        uint h[8];
        #pragma unroll
        for (int e = 0; e < 8; ++e) h[e] = f2bf(v[e]);
        hv = make_uint4(h[0] | (h[1] << 16), h[2] | (h[3] << 16),
                        h[4] | (h[5] << 16), h[6] | (h[7] << 16));
    }

    for (int kt = 0; kt < NKT; ++kt) {
        const int cur = kt & 1;

        __syncthreads();   // (a) prev compute done; drains B[cur] stage + x loads

        // ---- A write phase (pre-converted regs -> LDS, swizzled slot) ----
        if (stager)
            *reinterpret_cast<uint4*>(&Ah[sj][sslot][0]) = hv;

        __syncthreads();   // (b) A visible (lgkm drain only)

        // ---- prefetch next A floats first, then next B tile stage ----
        float4 xa, xb;
        if (kt + 1 < NKT) {
            if (stager) {
                xa = *reinterpret_cast<const float4*>(xsrc + (kt + 1) * BK);
                xb = *reinterpret_cast<const float4*>(xsrc + (kt + 1) * BK + 4);
            }
            const int nxt = cur ^ 1;
            const char* sH = wsChi + (size_t)(kt + 1) * 32768 + w * 4096 + lane * 16;
            char* dH = ((char*)Bh) + nxt * BBUF_BYTES + w * 4096;
            #pragma unroll
            for (int i = 0; i < 4; ++i) GLOAD16(sH + i * 1024, dH + i * 1024);
        }

        // ---- compute: 2 k-steps of 16, 4 MFMAs each ----
        __builtin_amdgcn_s_setprio(1);
        #pragma unroll
        for (int ks = 0; ks < 2; ++ks) {
            const int j = ks * 2 + lh;
            const int rsl = (wm * 32 + l31) ^ (j << 1);   // read slot (swizzle inverse)
            bf16x8 ah0 = *(const bf16x8*)&Ah[j][rsl][0];

            const ushort* pBh = &Bh[cur][j][wn * 128 + l31][0];
            #pragma unroll
            for (int nf = 0; nf < 4; ++nf) {
                bf16x8 bh = *(const bf16x8*)(pBh + nf * 32 * 8);
                acc[nf] = __builtin_amdgcn_mfma_f32_32x32x16_bf16(ah0, bh, acc[nf], 0, 0, 0);
            }
        }
        __builtin_amdgcn_s_setprio(0);

        // ---- convert next A tile (loads issued above) ----
        if (stager && kt + 1 < NKT) {
            float v[8] = {xa.x, xa.y, xa.z, xa.w, xb.x, xb.y, xb.z, xb.w};
            uint h[8];
            #pragma unroll
            for (int e = 0; e < 8; ++e) h[e] = f2bf(v[e]);
            hv = make_uint4(h[0] | (h[1] << 16), h[2] | (h[3] << 16),
                            h[4] | (h[5] << 16), h[6] | (h[7] << 16));
        }
    }

    // ---- epilogue: per-row (best, second, idx) over this wave's 128 cols ----
    float cq[4];
    #pragma unroll
    for (int nf = 0; nf < 4; ++nf) cq[nf] = csq[wn * 128 + nf * 32 + l31];

    #pragma unroll
    for (int reg = 0; reg < 16; ++reg) {
        float v[4]; int col[4];
        #pragma unroll
        for (int nf = 0; nf < 4; ++nf) {
            v[nf]   = fmaf(-2.f, acc[nf][reg], cq[nf]);
            col[nf] = wn * 128 + nf * 32 + l31;
        }
        float paL, paH; int paI;
        if (v[1] < v[0]) { paL = v[1]; paI = col[1]; paH = v[0]; }
        else             { paL = v[0]; paI = col[0]; paH = v[1]; }
        float pbL, pbH; int pbI;
        if (v[3] < v[2]) { pbL = v[3]; pbI = col[3]; pbH = v[2]; }
        else             { pbL = v[2]; pbI = col[2]; pbH = v[3]; }
        float b1, b2; int i1;
        if (pbL < paL) { b1 = pbL; i1 = pbI; b2 = fminf(paL, pbH); }
        else           { b1 = paL; i1 = paI; b2 = fminf(pbL, paH); }
        #pragma unroll
        for (int m = 1; m < 32; m <<= 1) {
            float o1 = __shfl_xor(b1, m, 64);
            float o2 = __shfl_xor(b2, m, 64);
            int   oi = __shfl_xor(i1, m, 64);
            b2 = fminf(fminf(b2, o2), fmaxf(b1, o1));
            if (o1 < b1 || (o1 == b1 && oi < i1)) { b1 = o1; i1 = oi; }
        }
        int row = wm * 32 + (reg & 3) + 8 * (reg >> 2) + 4 * lh;
        if (l31 == 0) { rv1[wn][row] = b1; rv2[wn][row] = b2; ridx[wn][row] = i1; }
    }
    __syncthreads();

    // ---- merge 4 col-quarters per row, write out, flag tight margins ----
    if (tid < BM) {
        float b1 = INFINITY, b2 = INFINITY; int i1 = 0;
        #pragma unroll
        for (int ww = 0; ww < 4; ++ww) {
            float a1 = rv1[ww][tid], a2 = rv2[ww][tid];
            int   ai = ridx[ww][tid];
            b2 = fminf(fminf(b2, a2), fmaxf(b1, a1));
            if (a1 < b1 || (a1 == b1 && ai < i1)) { b1 = a1; i1 = ai; }
        }
        out[rowBase + tid] = i1;
        if (b2 - b1 < TAU) {
            int p = atomicAdd(count, 1);
            list[p] = rowBase + tid;
        }
    }
}

// ---------------------------------------------------------------------------
// Rescue v2: exact fp32 recompute, 8 rows per block staged in LDS.
// Wave w owns centers [w*125, (w+1)*125); lane l covers dims l+64j (coalesced
// center reads); butterfly reduce for the dot.
// ---------------------------------------------------------------------------
__global__ __launch_bounds__(256) void rescue_kernel(
        const float* __restrict__ x, const float* __restrict__ c,
        const char* __restrict__ ws, int* __restrict__ out) {
    __shared__ float xs[RG][DIM];     // 24 KB
    __shared__ float wbv[4][RG];
    __shared__ int   wbi[4][RG];
    __shared__ int   rows_s[RG];
    const float* csq = (const float*)(ws + WS_CSQ);
    const int* list  = (const int*)(ws + WS_LIST);
    const int n = *(const int*)ws;
    const int tid  = threadIdx.x;
    const int w    = tid >> 6;
    const int lane = tid & 63;

    for (int g = blockIdx.x; g * RG < n; g += gridDim.x) {
        const int base = g * RG;
        const int cnt = min(RG, n - base);
        if (tid < cnt) rows_s[tid] = list[base + tid];
        __syncthreads();
        for (int idx = tid; idx < cnt * DIM; idx += 256) {
            int r = idx / DIM, d = idx - r * DIM;
            xs[r][d] = x[(size_t)rows_s[r] * DIM + d];
        }
        __syncthreads();

        float bv[RG]; int bi[RG];
        #pragma unroll
        for (int r = 0; r < RG; ++r) { bv[r] = INFINITY; bi[r] = 0; }

        const int k0 = w * 125, k1 = k0 + 125;
        for (int k = k0; k < k1; ++k) {
            const float* crow = c + (size_t)k * DIM;
            float cv[12];
            #pragma unroll
            for (int j = 0; j < 12; ++j) cv[j] = crow[lane + 64 * j];
            float p[RG];
            #pragma unroll
            for (int r = 0; r < RG; ++r) {
                float s = 0.f;
                #pragma unroll
                for (int j = 0; j < 12; ++j) s = fmaf(xs[r][lane + 64 * j], cv[j], s);
                p[r] = s;
            }
            #pragma unroll
            for (int m = 1; m < 64; m <<= 1) {
                #pragma unroll
                for (int r = 0; r < RG; ++r) p[r] += __shfl_xor(p[r], m, 64);
            }
            const float cq = csq[k];
            #pragma unroll
            for (int r = 0; r < RG; ++r) {
                float dist = fmaf(-2.f, p[r], cq);
                if (dist < bv[r]) { bv[r] = dist; bi[r] = k; }   // k ascending: ties keep lower
            }
        }
        if (lane == 0) {
            #pragma unroll
            for (int r = 0; r < RG; ++r) { wbv[w][r] = bv[r]; wbi[w][r] = bi[r]; }
        }
        __syncthreads();
        if (tid < cnt) {
            float b = wbv[0][tid]; int i = wbi[0][tid];
            #pragma unroll
            for (int ww = 1; ww < 4; ++ww) {
                if (wbv[ww][tid] < b) { b = wbv[ww][tid]; i = wbi[ww][tid]; }
            }
            out[rows_s[tid]] = i;
        }
        __syncthreads();
    }
}

extern "C" void kernel_launch(void* const* d_in, const int* in_sizes, int n_in,
                              void* d_out, int out_size, void* d_ws, size_t ws_size,
                              hipStream_t stream) {
    const float* x = (const float*)d_in[0];
    const float* c = (const float*)d_in[1];
    char* ws = (char*)d_ws;
    int* out = (int*)d_out;

    convert_kernel<<<dim3(192), dim3(256), 0, stream>>>(
        c, (ushort*)(ws + WS_CHI), (int*)ws);
    csq_kernel<<<dim3(128), dim3(256), 0, stream>>>(c, (float*)(ws + WS_CSQ));
    kmeans_mfma<<<dim3(NROWS / BM), dim3(THREADS), 0, stream>>>(x, ws, out);
    rescue_kernel<<<dim3(512), dim3(256), 0, stream>>>(x, c, ws, out);
}

// Round 8
// 249.481 us; speedup vs baseline: 2.4234x; 1.0955x over previous
//
#include <hip/hip_runtime.h>

#define K_C    500
#define KPAD   512
#define DIM    768
#define NROWS  65536
#define BM     64
#define BK     32
#define NKT    (DIM / BK)      // 24 K-tiles
#define THREADS 512
#define TAU    1.0f
#define RROWS  16              // rescue rows per block

// Per-buffer LDS stride for B double-buffer: 4 chunks x 512 centers x 8 ushorts
#define BBUF_BYTES 32768

// ---- d_ws layout (bytes) ----
#define WS_CSQ  64
#define WS_LIST 4096
#define WS_CHI  270336

typedef __attribute__((ext_vector_type(8)))  short bf16x8;
typedef __attribute__((ext_vector_type(16))) float f32x16;

__device__ __forceinline__ ushort f2bf(float f) {
    unsigned x = __float_as_uint(f);
    unsigned r = (x + 0x7fffu + ((x >> 16) & 1u)) >> 16;   // RNE
    return (ushort)r;
}

#define GLOAD16(g, l)                                                        \
    __builtin_amdgcn_global_load_lds(                                        \
        (__attribute__((address_space(1))) void*)(g),                        \
        (__attribute__((address_space(3))) void*)(l), 16, 0, 0)

// ---------------------------------------------------------------------------
// Pre-kernel 1: centers fp32 -> bf16 (RNE), chunk-major tile layout:
// unit u = kt*2048 + j*512 + r holds c[r][kt*32 + j*8 .. +7]. Zero-pads
// rows 500..511 and zeroes the rescue counter.
// ---------------------------------------------------------------------------
__global__ void convert_kernel(const float* __restrict__ c, ushort* __restrict__ chi,
                               int* __restrict__ count) {
    int gid = blockIdx.x * 256 + threadIdx.x;
    if (gid == 0) *count = 0;
    int kt = gid >> 11;
    int u  = gid & 2047;
    int j  = u >> 9;
    int r  = u & 511;
    int kbase = kt * 32 + j * 8;

    ushort h[8];
    if (r < K_C) {
        #pragma unroll
        for (int e = 0; e < 8; ++e) h[e] = f2bf(c[(size_t)r * DIM + kbase + e]);
    } else {
        #pragma unroll
        for (int e = 0; e < 8; ++e) h[e] = 0;
    }
    ushort* ph = chi + (size_t)gid * 8;
    #pragma unroll
    for (int e = 0; e < 8; ++e) ph[e] = h[e];
}

// ---------------------------------------------------------------------------
// Pre-kernel 2: csq[k] = ||c_k||^2 fp32; pads 500..511 with +INF.
// ---------------------------------------------------------------------------
__global__ void csq_kernel(const float* __restrict__ c, float* __restrict__ csq) {
    int wid  = (blockIdx.x * blockDim.x + threadIdx.x) >> 6;
    int lane = threadIdx.x & 63;
    if (wid >= KPAD) return;
    if (wid >= K_C) { if (lane == 0) csq[wid] = INFINITY; return; }
    const float* row = c + (size_t)wid * DIM;
    float s = 0.f;
    #pragma unroll
    for (int j = 0; j < DIM / 64; ++j) {
        float v = row[lane + j * 64];
        s += v * v;
    }
    #pragma unroll
    for (int m = 32; m; m >>= 1) s += __shfl_xor(s, m, 64);
    if (lane == 0) csq[wid] = s;
}

// ---------------------------------------------------------------------------
// Main kernel (unchanged from round 7): 64 rows x 512 centers per block,
// grid 1024, 8 waves = 2(m) x 4(n), acc 64 regs, launch_bounds(512,4) ->
// 2 blocks/CU. 1-term bf16 GEMM; TAU=1.0 flags rows for exact fp32 rescue.
// ---------------------------------------------------------------------------
__global__ __launch_bounds__(THREADS, 4) void kmeans_mfma(
        const float* __restrict__ x, const char* __restrict__ ws,
        int* __restrict__ out) {
    __shared__ __align__(16) ushort Bh[2][4][KPAD][8];   // 64 KB
    __shared__ __align__(16) ushort Ah[4][BM][8];        // 4 KB
    __shared__ float rv1[4][BM];                         // 1 KB
    __shared__ float rv2[4][BM];                         // 1 KB
    __shared__ int   ridx[4][BM];                        // 1 KB

    const int tid  = threadIdx.x;
    const int w    = tid >> 6;          // wave 0..7
    const int lane = tid & 63;
    const int l31  = lane & 31;
    const int lh   = lane >> 5;
    const int wm   = w >> 2;            // 0..1 row half (32 rows each)
    const int wn   = w & 3;             // 0..3 col quarter (128 cols each)
    const int rowBase = blockIdx.x * BM;

    // A staging (threads 0..255): thread t -> row t>>2 (0..63), k-chunk j = t&3
    const int srow = tid >> 2;
    const int sj   = tid & 3;
    const int sslot = srow ^ (sj << 1);   // bank-conflict-free write slot
    const bool stager = (tid < 256);
    const float* xsrc = x + (size_t)(rowBase + srow) * DIM + sj * 8;

    const char* wsChi = ws + WS_CHI;
    const float* csq  = (const float*)(ws + WS_CSQ);
    int* count = (int*)ws;
    int* list  = (int*)(ws + WS_LIST);

    f32x16 acc[4] = {};

    // ---- prologue: stage B tile 0 into buf 0; load+convert A tile 0 ----
    {
        const char* sH = wsChi + w * 4096 + lane * 16;
        char* dH = ((char*)Bh) + w * 4096;
        #pragma unroll
        for (int i = 0; i < 4; ++i) GLOAD16(sH + i * 1024, dH + i * 1024);
    }
    uint4 hv;
    if (stager) {
        float4 xa = *reinterpret_cast<const float4*>(xsrc);
        float4 xb = *reinterpret_cast<const float4*>(xsrc + 4);
        float v[8] = {xa.x, xa.y, xa.z, xa.w, xb.x, xb.y, xb.z, xb.w};
        uint h[8];
        #pragma unroll
        for (int e = 0; e < 8; ++e) h[e] = f2bf(v[e]);
        hv = make_uint4(h[0] | (h[1] << 16), h[2] | (h[3] << 16),
                        h[4] | (h[5] << 16), h[6] | (h[7] << 16));
    }

    for (int kt = 0; kt < NKT; ++kt) {
        const int cur = kt & 1;

        __syncthreads();   // (a) prev compute done; drains B[cur] stage + x loads

        // ---- A write phase (pre-converted regs -> LDS, swizzled slot) ----
        if (stager)
            *reinterpret_cast<uint4*>(&Ah[sj][sslot][0]) = hv;

        __syncthreads();   // (b) A visible (lgkm drain only)

        // ---- prefetch next A floats first, then next B tile stage ----
        float4 xa, xb;
        if (kt + 1 < NKT) {
            if (stager) {
                xa = *reinterpret_cast<const float4*>(xsrc + (kt + 1) * BK);
                xb = *reinterpret_cast<const float4*>(xsrc + (kt + 1) * BK + 4);
            }
            const int nxt = cur ^ 1;
            const char* sH = wsChi + (size_t)(kt + 1) * 32768 + w * 4096 + lane * 16;
            char* dH = ((char*)Bh) + nxt * BBUF_BYTES + w * 4096;
            #pragma unroll
            for (int i = 0; i < 4; ++i) GLOAD16(sH + i * 1024, dH + i * 1024);
        }

        // ---- compute: 2 k-steps of 16, 4 MFMAs each ----
        __builtin_amdgcn_s_setprio(1);
        #pragma unroll
        for (int ks = 0; ks < 2; ++ks) {
            const int j = ks * 2 + lh;
            const int rsl = (wm * 32 + l31) ^ (j << 1);   // read slot (swizzle inverse)
            bf16x8 ah0 = *(const bf16x8*)&Ah[j][rsl][0];

            const ushort* pBh = &Bh[cur][j][wn * 128 + l31][0];
            #pragma unroll
            for (int nf = 0; nf < 4; ++nf) {
                bf16x8 bh = *(const bf16x8*)(pBh + nf * 32 * 8);
                acc[nf] = __builtin_amdgcn_mfma_f32_32x32x16_bf16(ah0, bh, acc[nf], 0, 0, 0);
            }
        }
        __builtin_amdgcn_s_setprio(0);

        // ---- convert next A tile (loads issued above) ----
        if (stager && kt + 1 < NKT) {
            float v[8] = {xa.x, xa.y, xa.z, xa.w, xb.x, xb.y, xb.z, xb.w};
            uint h[8];
            #pragma unroll
            for (int e = 0; e < 8; ++e) h[e] = f2bf(v[e]);
            hv = make_uint4(h[0] | (h[1] << 16), h[2] | (h[3] << 16),
                            h[4] | (h[5] << 16), h[6] | (h[7] << 16));
        }
    }

    // ---- epilogue: per-row (best, second, idx) over this wave's 128 cols ----
    float cq[4];
    #pragma unroll
    for (int nf = 0; nf < 4; ++nf) cq[nf] = csq[wn * 128 + nf * 32 + l31];

    #pragma unroll
    for (int reg = 0; reg < 16; ++reg) {
        float v[4]; int col[4];
        #pragma unroll
        for (int nf = 0; nf < 4; ++nf) {
            v[nf]   = fmaf(-2.f, acc[nf][reg], cq[nf]);
            col[nf] = wn * 128 + nf * 32 + l31;
        }
        float paL, paH; int paI;
        if (v[1] < v[0]) { paL = v[1]; paI = col[1]; paH = v[0]; }
        else             { paL = v[0]; paI = col[0]; paH = v[1]; }
        float pbL, pbH; int pbI;
        if (v[3] < v[2]) { pbL = v[3]; pbI = col[3]; pbH = v[2]; }
        else             { pbL = v[2]; pbI = col[2]; pbH = v[3]; }
        float b1, b2; int i1;
        if (pbL < paL) { b1 = pbL; i1 = pbI; b2 = fminf(paL, pbH); }
        else           { b1 = paL; i1 = paI; b2 = fminf(pbL, paH); }
        #pragma unroll
        for (int m = 1; m < 32; m <<= 1) {
            float o1 = __shfl_xor(b1, m, 64);
            float o2 = __shfl_xor(b2, m, 64);
            int   oi = __shfl_xor(i1, m, 64);
            b2 = fminf(fminf(b2, o2), fmaxf(b1, o1));
            if (o1 < b1 || (o1 == b1 && oi < i1)) { b1 = o1; i1 = oi; }
        }
        int row = wm * 32 + (reg & 3) + 8 * (reg >> 2) + 4 * lh;
        if (l31 == 0) { rv1[wn][row] = b1; rv2[wn][row] = b2; ridx[wn][row] = i1; }
    }
    __syncthreads();

    // ---- merge 4 col-quarters per row, write out, flag tight margins ----
    if (tid < BM) {
        float b1 = INFINITY, b2 = INFINITY; int i1 = 0;
        #pragma unroll
        for (int ww = 0; ww < 4; ++ww) {
            float a1 = rv1[ww][tid], a2 = rv2[ww][tid];
            int   ai = ridx[ww][tid];
            b2 = fminf(fminf(b2, a2), fmaxf(b1, a1));
            if (a1 < b1 || (a1 == b1 && ai < i1)) { b1 = a1; i1 = ai; }
        }
        out[rowBase + tid] = i1;
        if (b2 - b1 < TAU) {
            int p = atomicAdd(count, 1);
            list[p] = rowBase + tid;
        }
    }
}

// ---------------------------------------------------------------------------
// Rescue v3: exact fp32, VALU-bound. 16 rows/block staged in LDS; each of
// 256 threads owns centers {2t, 2t+1} and streams them from global
// (L2-resident), computing dots vs all 16 rows simultaneously (x reads are
// wave-uniform LDS broadcasts). Argmin reduce happens ONCE per block:
// 6 shuffle stages x 16 rows, then cross-wave merge (waves own ascending
// k-ranges -> strict < keeps lowest index).
// ---------------------------------------------------------------------------
__global__ __launch_bounds__(256) void rescue_kernel(
        const float* __restrict__ x, const float* __restrict__ c,
        const char* __restrict__ ws, int* __restrict__ out) {
    __shared__ __align__(16) float xs[RROWS][DIM];   // 48 KB
    __shared__ float rbv[4][RROWS];
    __shared__ int   rbi[4][RROWS];
    __shared__ int   rows_s[RROWS];
    const float* csq = (const float*)(ws + WS_CSQ);
    const int* list  = (const int*)(ws + WS_LIST);
    const int n = *(const int*)ws;
    const int tid  = threadIdx.x;
    const int w    = tid >> 6;
    const int lane = tid & 63;
    const int k0 = tid * 2;
    const int k1 = tid * 2 + 1;
    // clamp row pointers for padded (k>=500) threads; csq pad = +INF keeps
    // their distances out of the argmin.
    const float* c0 = c + (size_t)min(k0, K_C - 1) * DIM;
    const float* c1 = c + (size_t)min(k1, K_C - 1) * DIM;
    const float cq0 = csq[k0];
    const float cq1 = csq[k1];

    for (int g = blockIdx.x; g * RROWS < n; g += gridDim.x) {
        const int base = g * RROWS;
        const int cnt  = min(RROWS, n - base);
        if (tid < RROWS) rows_s[tid] = list[base + min(tid, cnt - 1)];
        __syncthreads();
        #pragma unroll 2
        for (int idx = tid; idx < RROWS * (DIM / 4); idx += 256) {
            int r = idx / (DIM / 4), dc = idx - r * (DIM / 4);
            *reinterpret_cast<float4*>(&xs[r][dc * 4]) =
                *reinterpret_cast<const float4*>(&x[(size_t)rows_s[r] * DIM + dc * 4]);
        }
        __syncthreads();

        float dot0[RROWS], dot1[RROWS];
        #pragma unroll
        for (int r = 0; r < RROWS; ++r) { dot0[r] = 0.f; dot1[r] = 0.f; }

        #pragma unroll 2
        for (int d = 0; d < DIM; d += 4) {
            float4 cv0 = *reinterpret_cast<const float4*>(&c0[d]);
            float4 cv1 = *reinterpret_cast<const float4*>(&c1[d]);
            #pragma unroll
            for (int r = 0; r < RROWS; ++r) {
                float4 xv = *reinterpret_cast<const float4*>(&xs[r][d]);
                dot0[r] = fmaf(xv.x, cv0.x, dot0[r]);
                dot0[r] = fmaf(xv.y, cv0.y, dot0[r]);
                dot0[r] = fmaf(xv.z, cv0.z, dot0[r]);
                dot0[r] = fmaf(xv.w, cv0.w, dot0[r]);
                dot1[r] = fmaf(xv.x, cv1.x, dot1[r]);
                dot1[r] = fmaf(xv.y, cv1.y, dot1[r]);
                dot1[r] = fmaf(xv.z, cv1.z, dot1[r]);
                dot1[r] = fmaf(xv.w, cv1.w, dot1[r]);
            }
        }

        float bv[RROWS]; int bi[RROWS];
        #pragma unroll
        for (int r = 0; r < RROWS; ++r) {
            float v0 = fmaf(-2.f, dot0[r], cq0);
            float v1 = fmaf(-2.f, dot1[r], cq1);
            if (v1 < v0) { bv[r] = v1; bi[r] = k1; }
            else         { bv[r] = v0; bi[r] = k0; }
        }
        // wave argmin reduce (once per block, not per center)
        #pragma unroll
        for (int m = 1; m < 64; m <<= 1) {
            #pragma unroll
            for (int r = 0; r < RROWS; ++r) {
                float ov = __shfl_xor(bv[r], m, 64);
                int   oi = __shfl_xor(bi[r], m, 64);
                if (ov < bv[r] || (ov == bv[r] && oi < bi[r])) { bv[r] = ov; bi[r] = oi; }
            }
        }
        if (lane == 0) {
            #pragma unroll
            for (int r = 0; r < RROWS; ++r) { rbv[w][r] = bv[r]; rbi[w][r] = bi[r]; }
        }
        __syncthreads();
        if (tid < cnt) {
            float b = rbv[0][tid]; int i = rbi[0][tid];
            #pragma unroll
            for (int ww = 1; ww < 4; ++ww) {   // ascending k-ranges: strict < keeps lower idx
                if (rbv[ww][tid] < b) { b = rbv[ww][tid]; i = rbi[ww][tid]; }
            }
            out[rows_s[tid]] = i;
        }
        __syncthreads();   // before next group overwrites xs/rows_s
    }
}

extern "C" void kernel_launch(void* const* d_in, const int* in_sizes, int n_in,
                              void* d_out, int out_size, void* d_ws, size_t ws_size,
                              hipStream_t stream) {
    const float* x = (const float*)d_in[0];
    const float* c = (const float*)d_in[1];
    char* ws = (char*)d_ws;
    int* out = (int*)d_out;

    convert_kernel<<<dim3(192), dim3(256), 0, stream>>>(
        c, (ushort*)(ws + WS_CHI), (int*)ws);
    csq_kernel<<<dim3(128), dim3(256), 0, stream>>>(c, (float*)(ws + WS_CSQ));
    kmeans_mfma<<<dim3(NROWS / BM), dim3(THREADS), 0, stream>>>(x, ws, out);
    rescue_kernel<<<dim3(1024), dim3(256), 0, stream>>>(x, c, ws, out);
}